// Round 11
// baseline (27.360 us; speedup 1.0000x reference)
//
#include <hip/hip_runtime.h>

#define TT 262144
#define BB 16
#define SS 65536      // TT/4 quads per batch
#define QPB 512       // output quads per block
#define TILEQ 544     // QPB + 32 halo quads

// ---------------------------------------------------------------------------
// prep_w: build combined filter W only. One thread per (entry e, band k);
// 4-lane shfl reduce over k. W[p*132+i] with
//   out[4u+p] = sum_i W[p][i] * x[4u-64+i],
//   W[p][i]   = 4 * C_p[126+p-i],
//   C_p[dd]   = sum_k sum_{j==3-p (4)} H[k][124-j-dd] * G[k][j]
// ---------------------------------------------------------------------------
__global__ __launch_bounds__(256) void prep_w(const float* __restrict__ H,
                                              const float* __restrict__ G,
                                              float* __restrict__ W) {
    int t = blockIdx.x * 256 + threadIdx.x;   // 0..2303
    int e = t >> 2;
    int k = t & 3;
    bool valid = (e < 4 * 132);
    float acc = 0.f;
    if (valid) {
        int p = e / 132;
        int i = e % 132;
        int dd = 126 + p - i;                 // valid 0..124
        if (dd >= 0 && dd <= 124) {
            int j0 = (3 - p) & 3;
#pragma unroll
            for (int jj = 0; jj < 16; ++jj) {
                int j = j0 + 4 * jj;
                if (j <= 62) {
                    int a = 124 - j - dd;
                    if (a >= 0 && a <= 62) acc += H[k * 63 + a] * G[k * 63 + j];
                }
            }
        }
    }
    acc += __shfl_xor(acc, 1);
    acc += __shfl_xor(acc, 2);
    if (valid && k == 0) W[e] = 4.0f * acc;
}

// ---------------------------------------------------------------------------
// Fused PQMF. x tile staged in LDS (zero-padded halo); W read from GLOBAL
// with uniform indices -> scalar s_load path. 2 quads/thread strided by 64
// lanes; QPB=512 -> 8.7 KB LDS, ~48 VGPR -> 8 blocks/CU (32 waves/CU).
// Blocks 0 / gridDim.x-1 also compute the 16 edge quads each via the exact
// two-stage path (parallel over 16 s-slots), reading x from the staged tile.
// Phase mapping (validated rounds 2/8/9/10): out component p <- W4[33p + c].
// ---------------------------------------------------------------------------
__global__ __launch_bounds__(256) void pqmf_fused(const float* __restrict__ x,
                                                  const float* __restrict__ Wg,
                                                  const float* __restrict__ H,
                                                  const float* __restrict__ G,
                                                  float* __restrict__ out) {
    __shared__ float4 xs4[TILEQ];

    const int tid = threadIdx.x;
    const int b = blockIdx.y;
    const int Q0 = blockIdx.x * QPB;
    const float4* X4 = reinterpret_cast<const float4*>(x + (size_t)b * TT);

    // ---- stage x tile (zero-fill halo outside [0,SS)) ----
    const int gq0 = Q0 - 16;
    for (int j = tid; j < TILEQ; j += 256) {
        int gq = gq0 + j;
        xs4[j] = (gq >= 0 && gq < SS) ? X4[gq] : make_float4(0.f, 0.f, 0.f, 0.f);
    }
    __syncthreads();

    const int w = tid >> 6, l = tid & 63;
    const int base = w * 128 + l;        // block-local quad of stream 0

    float4 a0 = make_float4(0.f, 0.f, 0.f, 0.f);
    float4 a1 = a0;

    const float4* W4 = reinterpret_cast<const float4*>(Wg);

#define ACCUM(ar, xv)                                                          \
    ar.x = fmaf(W0.w, xv.w, fmaf(W0.z, xv.z, fmaf(W0.y, xv.y, fmaf(W0.x, xv.x, ar.x)))); \
    ar.y = fmaf(W1.w, xv.w, fmaf(W1.z, xv.z, fmaf(W1.y, xv.y, fmaf(W1.x, xv.x, ar.y)))); \
    ar.z = fmaf(W2.w, xv.w, fmaf(W2.z, xv.z, fmaf(W2.y, xv.y, fmaf(W2.x, xv.x, ar.z)))); \
    ar.w = fmaf(W3.w, xv.w, fmaf(W3.z, xv.z, fmaf(W3.y, xv.y, fmaf(W3.x, xv.x, ar.w))));

#pragma unroll 3
    for (int c = 0; c < 33; ++c) {
        float4 W0 = W4[c];               // uniform -> s_load, phase 0 -> .x
        float4 W1 = W4[33 + c];          // phase 1 -> .y
        float4 W2 = W4[66 + c];          // phase 2 -> .z
        float4 W3 = W4[99 + c];          // phase 3 -> .w
        float4 xv0 = xs4[base + c];
        float4 xv1 = xs4[base + 64 + c];
        ACCUM(a0, xv0)
        ACCUM(a1, xv1)
    }
#undef ACCUM

    float4* ob4 = reinterpret_cast<float4*>(out + (size_t)b * TT);
    const int u0 = Q0 + base;
    if ((unsigned)(u0 - 16) < (unsigned)(SS - 32)) ob4[u0] = a0;
    if ((unsigned)(u0 + 64 - 16) < (unsigned)(SS - 32)) ob4[u0 + 64] = a1;

    // ---- edge quads (exact two-stage), only first/last block per batch ----
    const bool edgeLo = (blockIdx.x == 0);
    const bool edgeHi = (blockIdx.x == gridDim.x - 1);
    if (edgeLo || edgeHi) {
        const int q_local = tid >> 4;    // 0..15
        const int s_idx = tid & 15;      // 0..15
        const int u = edgeLo ? q_local : (SS - 16 + q_local);
        const int s = u - 7 + s_idx;
        float c0 = 0.f, c1 = 0.f, c2 = 0.f, c3 = 0.f;
        if (s >= 0 && s < SS) {
            const float* xsf = reinterpret_cast<const float*>(xs4);
            // x[xi] == xsf[xi - 4*Q0 + 64]; coverage verified for both edges
            const int lbase = 4 * s - 31 - 4 * Q0 + 64;
            float s0 = 0.f, s1 = 0.f, s2 = 0.f, s3 = 0.f;
#pragma unroll
            for (int a = 0; a < 63; ++a) {
                float xv = xsf[lbase + a];
                s0 += xv * H[a];
                s1 += xv * H[63 + a];
                s2 += xv * H[126 + a];
                s3 += xv * H[189 + a];
            }
            const int d4 = 4 * (s - u);  // -28..32
            {
                int j = d4 + 31;         // p = 0 (j can be 63 at s=u+8)
                if (j <= 62) c0 = s0 * G[j] + s1 * G[63 + j] + s2 * G[126 + j] + s3 * G[189 + j];
            }
            {
                int j = d4 + 30;         // p = 1, j in [2,62]
                c1 = s0 * G[j] + s1 * G[63 + j] + s2 * G[126 + j] + s3 * G[189 + j];
            }
            {
                int j = d4 + 29;         // p = 2, j in [1,61]
                c2 = s0 * G[j] + s1 * G[63 + j] + s2 * G[126 + j] + s3 * G[189 + j];
            }
            {
                int j = d4 + 28;         // p = 3, j in [0,60]
                c3 = s0 * G[j] + s1 * G[63 + j] + s2 * G[126 + j] + s3 * G[189 + j];
            }
        }
#pragma unroll
        for (int m = 8; m >= 1; m >>= 1) {
            c0 += __shfl_xor(c0, m);
            c1 += __shfl_xor(c1, m);
            c2 += __shfl_xor(c2, m);
            c3 += __shfl_xor(c3, m);
        }
        if (s_idx == 0) {
            float4 v = make_float4(4.f * c0, 4.f * c1, 4.f * c2, 4.f * c3);
            ob4[u] = v;
        }
    }
}

extern "C" void kernel_launch(void* const* d_in, const int* in_sizes, int n_in,
                              void* d_out, int out_size, void* d_ws, size_t ws_size,
                              hipStream_t stream) {
    const float* x = (const float*)d_in[0];
    const float* H = (const float*)d_in[1];
    const float* G = (const float*)d_in[2];
    float* outp = (float*)d_out;
    float* W = (float*)d_ws;   // 4*132 floats = 2112 B

    hipLaunchKernelGGL(prep_w, dim3(9), dim3(256), 0, stream, H, G, W);
    hipLaunchKernelGGL(pqmf_fused, dim3(SS / QPB, BB), dim3(256), 0, stream,
                       x, W, H, G, outp);
}